// Round 6
// baseline (253.362 us; speedup 1.0000x reference)
//
#include <hip/hip_runtime.h>
#include <stdint.h>

#define SQ 2048
#define DH 64

typedef __attribute__((ext_vector_type(8))) short bf16x8;
typedef __attribute__((ext_vector_type(4))) short bf16x4;
typedef __attribute__((ext_vector_type(4))) float f32x4;

// RNE f32->bf16 (Q only; one-time cost)
static __device__ __forceinline__ unsigned short f2bf_rne(float x) {
  union { float f; uint32_t u; } v; v.f = x;
  uint32_t u = v.u;
  return (unsigned short)((u + 0x7FFFu + ((u >> 16) & 1u)) >> 16);
}

// low16 = bf16_trunc(a), high16 = bf16_trunc(b) -- single v_perm_b32
static __device__ __forceinline__ uint32_t pack_hi(float a, float b) {
  uint32_t au = __float_as_uint(a), bu = __float_as_uint(b);
#if __has_builtin(__builtin_amdgcn_perm)
  return __builtin_amdgcn_perm(bu, au, 0x07060302u);
#else
  return (bu & 0xFFFF0000u) | (au >> 16);
#endif
}

// pack+mask fused: sel bytes 0x02,0x03 pick a's high half; 0x06,0x07 pick b's;
// 0x0C -> constant 0x00 (masked). NOTE: v_perm sel 8..11 are SIGN-REPLICATE,
// not zero -- 12 is the architectural zero byte.
static __device__ __forceinline__ uint32_t pack_sel(float a, float b, uint32_t sel) {
#if __has_builtin(__builtin_amdgcn_perm)
  return __builtin_amdgcn_perm(__float_as_uint(b), __float_as_uint(a), sel);
#else
  uint32_t r = 0;
  uint64_t src = ((uint64_t)__float_as_uint(b) << 32) | __float_as_uint(a);
  for (int i = 0; i < 4; ++i) {
    uint32_t sb = (sel >> (8 * i)) & 0xFF;
    uint32_t byte = (sb < 8) ? (uint32_t)((src >> (8 * sb)) & 0xFF) : 0u;
    r |= byte << (8 * i);
  }
  return r;
#endif
}

static __device__ __forceinline__ float fast_exp2(float x) {
#if __has_builtin(__builtin_amdgcn_exp2f)
  return __builtin_amdgcn_exp2f(x);
#else
  return exp2f(x);
#endif
}

// s_setprio requires a LITERAL constant argument -> dedicated wrappers.
static __device__ __forceinline__ void setprio_hi() {
#if __has_builtin(__builtin_amdgcn_s_setprio)
  __builtin_amdgcn_s_setprio(1);
#endif
}
static __device__ __forceinline__ void setprio_lo() {
#if __has_builtin(__builtin_amdgcn_s_setprio)
  __builtin_amdgcn_s_setprio(0);
#endif
}

static __device__ __forceinline__ void sched_barrier0() {
#if __has_builtin(__builtin_amdgcn_sched_barrier)
  __builtin_amdgcn_sched_barrier(0);
#endif
}

#if __has_builtin(__builtin_amdgcn_mfma_f32_16x16x16_bf16)
#define MFMA_PV(a, b, c) __builtin_amdgcn_mfma_f32_16x16x16_bf16((a), (b), (c), 0, 0, 0)
#else
#define MFMA_PV(a, b, c) __builtin_amdgcn_mfma_f32_16x16x16bf16_1k((a), (b), (c), 0, 0, 0)
#endif

// async global->LDS, 16B per lane. LDS dest is wave-uniform base + lane*16
// (HW rule); global src is per-lane.
typedef __attribute__((address_space(1))) const void as1_const_void;
typedef __attribute__((address_space(3))) void as3_void;
static __device__ __forceinline__ void gload_lds16(const void* g, void* l, int lane) {
#if __has_builtin(__builtin_amdgcn_global_load_lds)
  __builtin_amdgcn_global_load_lds((as1_const_void*)g, (as3_void*)l, 16, 0, 0);
#else
  *(uint4*)((char*)l + lane * 16) = *(const uint4*)g;
#endif
}

// ============================ merged pack kernel ============================
// blocks [0,2048): K/V bf16 pre-pack.
//   K: per (bh,tile): 64 kk x 8 chunks of 8 bf16; physical chunk cp holds
//      logical c = cp ^ (kk&7). 16-k sub-tiles are the 2KB quarters.
//   V: per (bh,tile): V^T u-major: uint2 at index u*64+d holds
//      {pack(V[4u][d],V[4u+1][d]), pack(V[4u+2][d],V[4u+3][d])}, u=k/4.
//      Each kt's 2KB sub-image (u in [kt*4,kt*4+4)) is contiguous ->
//      linear global_load_lds staging; LDS reads are 2-way (free).
// blocks [2048,6144): mask -> v_perm selector words (unchanged layout).
__global__ __launch_bounds__(256) void pack_all(const float* __restrict__ K,
                                                const float* __restrict__ V,
                                                const int* __restrict__ mask,
                                                uint4* __restrict__ pk,
                                                uint2* __restrict__ pv,
                                                uint2* __restrict__ pm) {
  const int t = threadIdx.x;
  if (blockIdx.x < 2048) {
    __shared__ uint32_t Vw[64][33];
    const int bt = blockIdx.x;  // bh*32 + tile
    {
      const float* src = K + (size_t)bt * 64 * DH;
      uint4* dst = pk + (size_t)bt * 512;
#pragma unroll
      for (int j = 0; j < 2; ++j) {
        int i = t + j * 256;
        int kk = i >> 3, cp = i & 7;
        int c = cp ^ (kk & 7);
        const float4* s4 = (const float4*)(src + (size_t)kk * DH + c * 8);
        float4 a = s4[0], b = s4[1];
        uint4 w;
        w.x = pack_hi(a.x, a.y); w.y = pack_hi(a.z, a.w);
        w.z = pack_hi(b.x, b.y); w.w = pack_hi(b.z, b.w);
        dst[i] = w;
      }
    }
    {
      const float* src = V + (size_t)bt * 64 * DH;
#pragma unroll
      for (int half = 0; half < 2; ++half) {
        int kp = (t >> 4) + half * 16;
        int d4 = (t & 15) * 4;
        float4 a = *(const float4*)(src + (size_t)(2 * kp) * DH + d4);
        float4 b = *(const float4*)(src + (size_t)(2 * kp + 1) * DH + d4);
        Vw[d4 + 0][kp] = pack_hi(a.x, b.x);
        Vw[d4 + 1][kp] = pack_hi(a.y, b.y);
        Vw[d4 + 2][kp] = pack_hi(a.z, b.z);
        Vw[d4 + 3][kp] = pack_hi(a.w, b.w);
      }
      __syncthreads();
      uint2* dst = pv + (size_t)bt * 1024;
#pragma unroll
      for (int j = 0; j < 4; ++j) {
        int o = t + j * 256;       // o = u*64 + d  (u-major, no XOR)
        int u = o >> 6, d = o & 63;
        uint2 w;
        w.x = Vw[d][2 * u]; w.y = Vw[d][2 * u + 1];
        dst[o] = w;
      }
    }
  } else {
    __shared__ uint2 Lm[16][17];
    const int bid = blockIdx.x - 2048;
    const int qb = bid >> 5, gb = bid & 31;
    {
      int qq = t >> 4, gg = t & 15;
      int4 m = *(const int4*)(mask + (size_t)(qb * 16 + qq) * SQ + (gb * 64 + gg * 4));
      uint2 w;
      w.x = (m.x ? 0x00000C0Cu : 0x00000302u) | (m.y ? 0x0C0C0000u : 0x07060000u);
      w.y = (m.z ? 0x00000C0Cu : 0x00000302u) | (m.w ? 0x0C0C0000u : 0x07060000u);
      Lm[gg][qq] = w;
    }
    __syncthreads();
    {
      int gg = t >> 4, qq = t & 15;
      pm[(size_t)(gb * 16 + gg) * 2048 + qb * 16 + qq] = Lm[gg][qq];
    }
  }
}

// Bitmask for fallback path
__global__ void pack_mask_kernel(const int* __restrict__ mask,
                                 unsigned long long* __restrict__ bits) {
  const int lane = threadIdx.x & 63;
  const int gw = (blockIdx.x * blockDim.x + threadIdx.x) >> 6;
  const int nw = (gridDim.x * blockDim.x) >> 6;
  for (int w = gw; w < SQ * SQ / 64; w += nw) {
    int v = mask[(size_t)w * 64 + lane];
    unsigned long long b = __ballot(v != 0);
    if (lane == 0) bits[(size_t)(w & 31) * SQ + (w >> 5)] = b;
  }
}

// ============================ main kernel ============================
// ROUND-5: barrier-free wave-private pipeline. Counters showed no pipe >45%
// busy at 3.1 waves/SIMD resident: the block-wide __syncthreads + vmcnt(0)
// drain per tile stalls all 4 waves in lockstep. Fix: each wave owns a
// private 8KB LDS slice (2 x 4KB buffers) and iterates 128 16-k sub-tiles:
//   [sched_barrier] issue 4 gload_lds(next) + 2 mask loads(next)
//   [s_waitcnt vmcnt(6) + sched_barrier]  <- counted, never 0: the 6 newest
//   stay in flight; everything older (this iter's buffers) is landed.
//   compute QK->exp2->pack+mask->PV on the current 4KB buffer.
// No __syncthreads in the loop -> waves free-run, stalls interleave.
// Ones-MFMA row-sum RESTORED (round-5 showed VALU row-sum hurt: VALU is the
// loaded pipe, MFMA had slack). setprio kept (independent-wave regime).
__global__ __launch_bounds__(256, 4) void attn5(
    const uint4* __restrict__ pk, const uint4* __restrict__ pv,
    const uint2* __restrict__ pm, const float* __restrict__ Qg,
    float* __restrict__ Og) {
  // per-wave: [wb, wb+4K) buf0 {K 2K | V 2K}, [wb+4K, wb+8K) buf1
  __shared__ __align__(16) uint8_t smem[32768];

  const int id = blockIdx.x;
  const int bh = id & 63;      // id%8 spreads bh across XCDs
  const int qblk = id >> 6;    // 0..15
  const int t = threadIdx.x;
  const int wave = t >> 6, lane = t & 63, col = lane & 15, quad = lane >> 4;

  const float* Qb = Qg + (size_t)bh * SQ * DH;
  float* Ob = Og + (size_t)bh * SQ * DH;
  const char* pkb = (const char*)(pk + (size_t)bh * 32 * 512);  // 256KB, 128 x 2KB sub-tiles
  const char* pvb = (const char*)(pv + (size_t)bh * 32 * 512);  // 256KB, 128 x 2KB sub-tiles
  const int q0 = qblk * 128 + wave * 32;

  // Q fragments, scale 1/8 * log2(e) folded in (scores emerge in log2 domain)
  const float QSCALE = 0.18033688011112042f;
  bf16x8 qf[2][2];
#pragma unroll
  for (int s = 0; s < 2; ++s) {
    int q = q0 + s * 16 + col;
#pragma unroll
    for (int j = 0; j < 2; ++j) {
      const float4* p = (const float4*)(Qb + (size_t)q * DH + j * 32 + quad * 8);
      float4 a = p[0], b = p[1];
      bf16x8 f;
      f[0] = (short)f2bf_rne(a.x * QSCALE); f[1] = (short)f2bf_rne(a.y * QSCALE);
      f[2] = (short)f2bf_rne(a.z * QSCALE); f[3] = (short)f2bf_rne(a.w * QSCALE);
      f[4] = (short)f2bf_rne(b.x * QSCALE); f[5] = (short)f2bf_rne(b.y * QSCALE);
      f[6] = (short)f2bf_rne(b.z * QSCALE); f[7] = (short)f2bf_rne(b.w * QSCALE);
      qf[s][j] = f;
    }
  }

  // loop-invariant offsets (within a 2KB K / 2KB V sub-image)
  const unsigned wb = (unsigned)wave * 8192u;
  const unsigned ka0 = col * 128 + ((quad ^ (col & 7)) * 16);
  const unsigned ka1 = col * 128 + (((4 + quad) ^ (col & 7)) * 16);
  const unsigned vb0 = 2048u + quad * 512u + col * 8u;  // + dt*128
  const char* pmt = (const char*)pm + (size_t)(quad * 2048 + q0 + col) * 8;

  f32x4 acc[2][4];  // O^T: row(d_local)=quad*4+r, col=q_local
  f32x4 accl[2];    // ones-MFMA row-sum (all 4 regs identical)
#pragma unroll
  for (int s = 0; s < 2; ++s) {
#pragma unroll
    for (int dt = 0; dt < 4; ++dt)
#pragma unroll
      for (int r = 0; r < 4; ++r) acc[s][dt][r] = 0.0f;
#pragma unroll
    for (int r = 0; r < 4; ++r) accl[s][r] = 0.0f;
  }
  bf16x4 vones;
  vones[0] = (short)0x3F80; vones[1] = (short)0x3F80;
  vones[2] = (short)0x3F80; vones[3] = (short)0x3F80;
  const f32x4 fz = {0.0f, 0.0f, 0.0f, 0.0f};

  // prologue: stage it=0 into buf0 + load its mask words (6 vm ops)
  gload_lds16(pkb + lane * 16,        smem + wb,        lane);
  gload_lds16(pkb + 1024 + lane * 16, smem + wb + 1024, lane);
  gload_lds16(pvb + lane * 16,        smem + wb + 2048, lane);
  gload_lds16(pvb + 1024 + lane * 16, smem + wb + 3072, lane);
  uint2 mwc0 = *(const uint2*)(pmt);
  uint2 mwc1 = *(const uint2*)(pmt + 128);
  unsigned bo = 0;

#pragma unroll 2
  for (int it = 0; it < 128; ++it) {
    // last iter re-stages it=127 (harmless) to keep the vmcnt count uniform
    const int itn = (it < 127) ? it + 1 : 127;
    const unsigned ob = bo ^ 4096u;

    sched_barrier0();  // staging must not hoist above prior iter's LDS reads
    const char* sk = pkb + (size_t)itn * 2048;
    const char* sv = pvb + (size_t)itn * 2048;
    gload_lds16(sk + lane * 16,        smem + wb + ob,        lane);
    gload_lds16(sk + 1024 + lane * 16, smem + wb + ob + 1024, lane);
    gload_lds16(sv + lane * 16,        smem + wb + ob + 2048, lane);
    gload_lds16(sv + 1024 + lane * 16, smem + wb + ob + 3072, lane);
    const char* pmn = pmt + (size_t)itn * 65536;
    uint2 mwn0 = *(const uint2*)(pmn);
    uint2 mwn1 = *(const uint2*)(pmn + 128);

    // counted drain: 6 newest (this iter's issues) stay in flight;
    // current buffer's staging (issued last iter) is guaranteed landed.
    asm volatile("s_waitcnt vmcnt(6)" ::: "memory");
    sched_barrier0();  // LDS reads below must not hoist above the wait

    const bf16x8 kf0 = *(const bf16x8*)(smem + wb + bo + ka0);
    const bf16x8 kf1 = *(const bf16x8*)(smem + wb + bo + ka1);

    uint32_t pf[2][2];
    {
      f32x4 st = __builtin_amdgcn_mfma_f32_16x16x32_bf16(kf0, qf[0][0], fz, 0, 0, 0);
      st = __builtin_amdgcn_mfma_f32_16x16x32_bf16(kf1, qf[0][1], st, 0, 0, 0);
      pf[0][0] = pack_sel(fast_exp2(st[0]), fast_exp2(st[1]), mwc0.x);
      pf[0][1] = pack_sel(fast_exp2(st[2]), fast_exp2(st[3]), mwc0.y);
    }
    {
      f32x4 st = __builtin_amdgcn_mfma_f32_16x16x32_bf16(kf0, qf[1][0], fz, 0, 0, 0);
      st = __builtin_amdgcn_mfma_f32_16x16x32_bf16(kf1, qf[1][1], st, 0, 0, 0);
      pf[1][0] = pack_sel(fast_exp2(st[0]), fast_exp2(st[1]), mwc1.x);
      pf[1][1] = pack_sel(fast_exp2(st[2]), fast_exp2(st[3]), mwc1.y);
    }

    union { uint32_t u[2]; bf16x4 v; } pw0, pw1;
    pw0.u[0] = pf[0][0]; pw0.u[1] = pf[0][1];
    pw1.u[0] = pf[1][0]; pw1.u[1] = pf[1][1];
    accl[0] = MFMA_PV(vones, pw0.v, accl[0]);
    accl[1] = MFMA_PV(vones, pw1.v, accl[1]);
    setprio_hi();
#pragma unroll
    for (int dt = 0; dt < 4; ++dt) {
      union { uint2 u2; bf16x4 v; } vf;
      vf.u2 = *(const uint2*)(smem + wb + bo + vb0 + dt * 128);
      acc[0][dt] = MFMA_PV(vf.v, pw0.v, acc[0][dt]);
      acc[1][dt] = MFMA_PV(vf.v, pw1.v, acc[1][dt]);
    }
    setprio_lo();

    mwc0 = mwn0; mwc1 = mwn1;
    bo = ob;
  }

  // ---- epilogue ----
#pragma unroll
  for (int s = 0; s < 2; ++s) {
    float inv = 1.0f / accl[s][0];
    int q = q0 + s * 16 + col;
    float* orow = Ob + (size_t)q * DH;
#pragma unroll
    for (int dt = 0; dt < 4; ++dt) {
      float4 o;
      o.x = acc[s][dt][0] * inv;
      o.y = acc[s][dt][1] * inv;
      o.z = acc[s][dt][2] * inv;
      o.w = acc[s][dt][3] * inv;
      *(float4*)(orow + dt * 16 + quad * 4) = o;
    }
  }
}

// ============================ fallback kernel (round-3 structure) ============================
__global__ __launch_bounds__(512, 4) void attn_fb(
    const float* __restrict__ Qg, const float* __restrict__ Kg,
    const float* __restrict__ Vg, const unsigned long long* __restrict__ mbits,
    const int* __restrict__ mraw, float* __restrict__ Og) {
  __shared__ __align__(16) unsigned short Klds[2][64][72];
  __shared__ __align__(16) uint32_t Vtlds[2][64][36];
  const int id = blockIdx.x;
  const int bh = id & 63;
  const int qblk = id >> 6;
  const int t = threadIdx.x;
  const int wave = t >> 6, lane = t & 63, col = lane & 15, quad = lane >> 4;
  const float* Qb = Qg + (size_t)bh * SQ * DH;
  const float* Kb = Kg + (size_t)bh * SQ * DH;
  const float* Vb = Vg + (size_t)bh * SQ * DH;
  float* Ob = Og + (size_t)bh * SQ * DH;
  const int q0 = qblk * 256 + wave * 32;
  const int skk = t >> 3, sd8 = (t & 7) * 8, skp = t >> 4, sd4 = (t & 15) * 4;
  const float QSCALE = 0.18033688011112042f;
  bf16x8 qf[2][2];
#pragma unroll
  for (int s = 0; s < 2; ++s) {
    int q = q0 + s * 16 + col;
#pragma unroll
    for (int j = 0; j < 2; ++j) {
      const float4* p = (const float4*)(Qb + (size_t)q * DH + j * 32 + quad * 8);
      float4 a = p[0], b = p[1];
      bf16x8 f;
      f[0] = (short)f2bf_rne(a.x * QSCALE); f[1] = (short)f2bf_rne(a.y * QSCALE);
      f[2] = (short)f2bf_rne(a.z * QSCALE); f[3] = (short)f2bf_rne(a.w * QSCALE);
      f[4] = (short)f2bf_rne(b.x * QSCALE); f[5] = (short)f2bf_rne(b.y * QSCALE);
      f[6] = (short)f2bf_rne(b.z * QSCALE); f[7] = (short)f2bf_rne(b.w * QSCALE);
      qf[s][j] = f;
    }
  }
  f32x4 acc[2][4]; f32x4 accl[2];
#pragma unroll
  for (int s = 0; s < 2; ++s) {
#pragma unroll
    for (int dt = 0; dt < 4; ++dt)
#pragma unroll
      for (int r = 0; r < 4; ++r) acc[s][dt][r] = 0.0f;
#pragma unroll
    for (int r = 0; r < 4; ++r) accl[s][r] = 0.0f;
  }
  bf16x4 vones;
  vones[0] = (short)0x3F80; vones[1] = (short)0x3F80;
  vones[2] = (short)0x3F80; vones[3] = (short)0x3F80;
  const f32x4 fz = {0.0f, 0.0f, 0.0f, 0.0f};
  auto load_mask = [&](int ti, unsigned long long m[2]) {
    if (mbits) {
#pragma unroll
      for (int s = 0; s < 2; ++s)
        m[s] = mbits[(size_t)ti * SQ + (q0 + s * 16 + col)];
    } else {
#pragma unroll
      for (int s = 0; s < 2; ++s) {
        int q = q0 + s * 16 + col;
        unsigned long long mm = 0;
#pragma unroll
        for (int j = 0; j < 4; ++j) {
          int4 mi = *(const int4*)(mraw + (size_t)q * SQ + ti * 64 + j * 16 + quad * 4);
          unsigned long long nib = (unsigned long long)((mi.x != 0) | ((mi.y != 0) << 1) |
                                                        ((mi.z != 0) << 2) | ((mi.w != 0) << 3));
          mm |= nib << (j * 16 + quad * 4);
        }
        m[s] = mm;
      }
    }
  };
  {
    const float4* kp = (const float4*)(Kb + (size_t)skk * DH + sd8);
    float4 k0 = kp[0], k1 = kp[1];
    const float* va = Vb + (size_t)(skp * 2) * DH + sd4;
    float4 v0 = *(const float4*)va, v1 = *(const float4*)(va + DH);
    uint4 kw;
    kw.x = pack_hi(k0.x, k0.y); kw.y = pack_hi(k0.z, k0.w);
    kw.z = pack_hi(k1.x, k1.y); kw.w = pack_hi(k1.z, k1.w);
    *(uint4*)&Klds[0][skk][sd8] = kw;
    Vtlds[0][sd4 + 0][skp] = pack_hi(v0.x, v1.x);
    Vtlds[0][sd4 + 1][skp] = pack_hi(v0.y, v1.y);
    Vtlds[0][sd4 + 2][skp] = pack_hi(v0.z, v1.z);
    Vtlds[0][sd4 + 3][skp] = pack_hi(v0.w, v1.w);
  }
  unsigned long long mcur[2];
  load_mask(0, mcur);
  for (int tile = 0; tile < 32; ++tile) {
    __syncthreads();
    const int cb = tile & 1, nb = cb ^ 1;
    const int tn = (tile + 1 < 32) ? tile + 1 : tile;
    const int kkn = tn * 64;
    const float4* kp = (const float4*)(Kb + (size_t)(kkn + skk) * DH + sd8);
    float4 k0 = kp[0], k1 = kp[1];
    const float* va = Vb + (size_t)(kkn + skp * 2) * DH + sd4;
    float4 v0 = *(const float4*)va;
    float4 v1 = *(const float4*)(va + DH);
    unsigned long long mnxt[2];
    load_mask(tn, mnxt);
    uint32_t pfw[2][4][2];
#pragma unroll
    for (int kt = 0; kt < 4; ++kt) {
      const bf16x8 kf0 = *(const bf16x8*)&Klds[cb][kt * 16 + col][quad * 8];
      const bf16x8 kf1 = *(const bf16x8*)&Klds[cb][kt * 16 + col][32 + quad * 8];
#pragma unroll
      for (int s = 0; s < 2; ++s) {
        f32x4 st = __builtin_amdgcn_mfma_f32_16x16x32_bf16(kf0, qf[s][0], fz, 0, 0, 0);
        st = __builtin_amdgcn_mfma_f32_16x16x32_bf16(kf1, qf[s][1], st, 0, 0, 0);
        uint32_t nib = (uint32_t)(mcur[s] >> (kt * 16 + quad * 4)) & 0xFu;
        float p[4];
#pragma unroll
        for (int r = 0; r < 4; ++r)
          p[r] = fast_exp2(((nib >> r) & 1u) ? -1.0e9f : st[r]);
        pfw[s][kt][0] = pack_hi(p[0], p[1]);
        pfw[s][kt][1] = pack_hi(p[2], p[3]);
      }
    }
    {
      uint4 kw;
      kw.x = pack_hi(k0.x, k0.y); kw.y = pack_hi(k0.z, k0.w);
      kw.z = pack_hi(k1.x, k1.y); kw.w = pack_hi(k1.z, k1.w);
      *(uint4*)&Klds[nb][skk][sd8] = kw;
      Vtlds[nb][sd4 + 0][skp] = pack_hi(v0.x, v1.x);
      Vtlds[nb][sd4 + 1][skp] = pack_hi(v0.y, v1.y);
      Vtlds[nb][sd4 + 2][skp] = pack_hi(v0.z, v1.z);
      Vtlds[nb][sd4 + 3][skp] = pack_hi(v0.w, v1.w);
    }
    mcur[0] = mnxt[0]; mcur[1] = mnxt[1];
#pragma unroll
    for (int kt = 0; kt < 4; ++kt) {
      union { uint32_t u[2]; bf16x4 v; } p0, p1;
      p0.u[0] = pfw[0][kt][0]; p0.u[1] = pfw[0][kt][1];
      p1.u[0] = pfw[1][kt][0]; p1.u[1] = pfw[1][kt][1];
      accl[0] = MFMA_PV(vones, p0.v, accl[0]);
      accl[1] = MFMA_PV(vones, p1.v, accl[1]);
#pragma unroll
      for (int dt = 0; dt < 4; ++dt) {
        union { uint2 u2; bf16x4 v; } cv;
        cv.u2 = *(const uint2*)&Vtlds[cb][dt * 16 + col][kt * 8 + quad * 2];
        acc[0][dt] = MFMA_PV(cv.v, p0.v, acc[0][dt]);
        acc[1][dt] = MFMA_PV(cv.v, p1.v, acc[1][dt]);
      }
    }
  }
#pragma unroll
  for (int s = 0; s < 2; ++s) {
    float inv = 1.0f / accl[s][0];
    int q = q0 + s * 16 + col;
    float* orow = Ob + (size_t)q * DH;
#pragma unroll
    for (int dt = 0; dt < 4; ++dt) {
      float4 o;
      o.x = acc[s][dt][0] * inv;
      o.y = acc[s][dt][1] * inv;
      o.z = acc[s][dt][2] * inv;
      o.w = acc[s][dt][3] * inv;
      *(float4*)(orow + dt * 16 + quad * 4) = o;
    }
  }
}

extern "C" void kernel_launch(void* const* d_in, const int* in_sizes, int n_in,
                              void* d_out, int out_size, void* d_ws, size_t ws_size,
                              hipStream_t stream) {
  const float* Q = (const float*)d_in[0];
  const float* K = (const float*)d_in[1];
  const float* V = (const float*)d_in[2];
  const int* mask = (const int*)d_in[3];
  float* out = (float*)d_out;

  const size_t PK_BYTES = (size_t)64 * 32 * 8192;  // 16 MB
  const size_t PV_BYTES = (size_t)64 * 32 * 8192;  // 16 MB
  const size_t PM_BYTES = (size_t)512 * 2048 * 8;  // 8 MB
  const size_t NEED = PK_BYTES + PV_BYTES + PM_BYTES;  // 40 MB

  if (ws_size >= NEED) {
    uint4* pk = (uint4*)d_ws;
    uint2* pv = (uint2*)((char*)d_ws + PK_BYTES);
    uint2* pm = (uint2*)((char*)d_ws + PK_BYTES + PV_BYTES);
    pack_all<<<6144, 256, 0, stream>>>(K, V, mask, pk, pv, pm);
    attn5<<<1024, 256, 0, stream>>>(pk, (uint4*)pv, pm, Q, out);
  } else if (ws_size >= (size_t)SQ * SQ / 8) {
    unsigned long long* bits = (unsigned long long*)d_ws;
    pack_mask_kernel<<<1024, 256, 0, stream>>>(mask, bits);
    attn_fb<<<512, 512, 0, stream>>>(Q, K, V, bits, mask, out);
  } else {
    attn_fb<<<512, 512, 0, stream>>>(Q, K, V, nullptr, mask, out);
  }
}

// Round 10
// 248.124 us; speedup vs baseline: 1.0211x; 1.0211x over previous
//
#include <hip/hip_runtime.h>
#include <stdint.h>

#define SQ 2048
#define DH 64

typedef __attribute__((ext_vector_type(8))) short bf16x8;
typedef __attribute__((ext_vector_type(4))) short bf16x4;
typedef __attribute__((ext_vector_type(4))) float f32x4;

// RNE f32->bf16 (Q only; one-time cost)
static __device__ __forceinline__ unsigned short f2bf_rne(float x) {
  union { float f; uint32_t u; } v; v.f = x;
  uint32_t u = v.u;
  return (unsigned short)((u + 0x7FFFu + ((u >> 16) & 1u)) >> 16);
}

// low16 = bf16_trunc(a), high16 = bf16_trunc(b) -- single v_perm_b32
static __device__ __forceinline__ uint32_t pack_hi(float a, float b) {
  uint32_t au = __float_as_uint(a), bu = __float_as_uint(b);
#if __has_builtin(__builtin_amdgcn_perm)
  return __builtin_amdgcn_perm(bu, au, 0x07060302u);
#else
  return (bu & 0xFFFF0000u) | (au >> 16);
#endif
}

// pack+mask fused: sel bytes 0x02,0x03 pick a's high half; 0x06,0x07 pick b's;
// 0x0C -> constant 0x00 (masked). NOTE: v_perm sel 8..11 are SIGN-REPLICATE,
// not zero -- 12 is the architectural zero byte.
static __device__ __forceinline__ uint32_t pack_sel(float a, float b, uint32_t sel) {
#if __has_builtin(__builtin_amdgcn_perm)
  return __builtin_amdgcn_perm(__float_as_uint(b), __float_as_uint(a), sel);
#else
  uint32_t r = 0;
  uint64_t src = ((uint64_t)__float_as_uint(b) << 32) | __float_as_uint(a);
  for (int i = 0; i < 4; ++i) {
    uint32_t sb = (sel >> (8 * i)) & 0xFF;
    uint32_t byte = (sb < 8) ? (uint32_t)((src >> (8 * sb)) & 0xFF) : 0u;
    r |= byte << (8 * i);
  }
  return r;
#endif
}

static __device__ __forceinline__ float fast_exp2(float x) {
#if __has_builtin(__builtin_amdgcn_exp2f)
  return __builtin_amdgcn_exp2f(x);
#else
  return exp2f(x);
#endif
}

#if __has_builtin(__builtin_amdgcn_mfma_f32_16x16x16_bf16)
#define MFMA_PV(a, b, c) __builtin_amdgcn_mfma_f32_16x16x16_bf16((a), (b), (c), 0, 0, 0)
#else
#define MFMA_PV(a, b, c) __builtin_amdgcn_mfma_f32_16x16x16bf16_1k((a), (b), (c), 0, 0, 0)
#endif

// async global->LDS, 16B per lane. LDS dest is wave-uniform base + lane*16
// (HW rule); global src is per-lane.
typedef __attribute__((address_space(1))) const void as1_const_void;
typedef __attribute__((address_space(3))) void as3_void;
static __device__ __forceinline__ void gload_lds16(const void* g, void* l, int lane) {
#if __has_builtin(__builtin_amdgcn_global_load_lds)
  __builtin_amdgcn_global_load_lds((as1_const_void*)g, (as3_void*)l, 16, 0, 0);
#else
  *(uint4*)((char*)l + lane * 16) = *(const uint4*)g;
#endif
}

// ============================ merged pack kernel ============================
// blocks [0,2048): K/V bf16 pre-pack in LDS-image XOR-swizzled layout.
//   K: per (bh,tile): 64 kk x 8 chunks of 8 bf16; physical chunk cp holds
//      logical c = cp ^ (kk&7).
//   V: per (bh,tile): V^T as [d][u'] uint2 (u = kk/4), u' = u ^ (d&15).
// blocks [2048,6144): mask -> v_perm selector words.
//   pm[g*2048+q] (g = tile*16+kt*4+quad) = uint2; word0 = selector for (kk0,kk1),
//   word1 = (kk2,kk3): keep -> pick bf16 bytes, masked -> 0x0C (zero byte).
__global__ __launch_bounds__(256) void pack_all(const float* __restrict__ K,
                                                const float* __restrict__ V,
                                                const int* __restrict__ mask,
                                                uint4* __restrict__ pk,
                                                uint2* __restrict__ pv,
                                                uint2* __restrict__ pm) {
  const int t = threadIdx.x;
  if (blockIdx.x < 2048) {
    __shared__ uint32_t Vw[64][33];
    const int bt = blockIdx.x;  // bh*32 + tile
    {
      const float* src = K + (size_t)bt * 64 * DH;
      uint4* dst = pk + (size_t)bt * 512;
#pragma unroll
      for (int j = 0; j < 2; ++j) {
        int i = t + j * 256;
        int kk = i >> 3, cp = i & 7;
        int c = cp ^ (kk & 7);
        const float4* s4 = (const float4*)(src + (size_t)kk * DH + c * 8);
        float4 a = s4[0], b = s4[1];
        uint4 w;
        w.x = pack_hi(a.x, a.y); w.y = pack_hi(a.z, a.w);
        w.z = pack_hi(b.x, b.y); w.w = pack_hi(b.z, b.w);
        dst[i] = w;
      }
    }
    {
      const float* src = V + (size_t)bt * 64 * DH;
#pragma unroll
      for (int half = 0; half < 2; ++half) {
        int kp = (t >> 4) + half * 16;
        int d4 = (t & 15) * 4;
        float4 a = *(const float4*)(src + (size_t)(2 * kp) * DH + d4);
        float4 b = *(const float4*)(src + (size_t)(2 * kp + 1) * DH + d4);
        Vw[d4 + 0][kp] = pack_hi(a.x, b.x);
        Vw[d4 + 1][kp] = pack_hi(a.y, b.y);
        Vw[d4 + 2][kp] = pack_hi(a.z, b.z);
        Vw[d4 + 3][kp] = pack_hi(a.w, b.w);
      }
      __syncthreads();
      uint2* dst = pv + (size_t)bt * 1024;
#pragma unroll
      for (int j = 0; j < 4; ++j) {
        int o = t + j * 256;
        int d = o >> 4, up = o & 15;
        int u = up ^ (d & 15);
        uint2 w;
        w.x = Vw[d][2 * u]; w.y = Vw[d][2 * u + 1];
        dst[o] = w;
      }
    }
  } else {
    __shared__ uint2 Lm[16][17];
    const int bid = blockIdx.x - 2048;
    const int qb = bid >> 5, gb = bid & 31;
    {
      int qq = t >> 4, gg = t & 15;
      int4 m = *(const int4*)(mask + (size_t)(qb * 16 + qq) * SQ + (gb * 64 + gg * 4));
      uint2 w;
      w.x = (m.x ? 0x00000C0Cu : 0x00000302u) | (m.y ? 0x0C0C0000u : 0x07060000u);
      w.y = (m.z ? 0x00000C0Cu : 0x00000302u) | (m.w ? 0x0C0C0000u : 0x07060000u);
      Lm[gg][qq] = w;
    }
    __syncthreads();
    {
      int gg = t >> 4, qq = t & 15;
      pm[(size_t)(gb * 16 + gg) * 2048 + qb * 16 + qq] = Lm[gg][qq];
    }
  }
}

// Bitmask for fallback path
__global__ void pack_mask_kernel(const int* __restrict__ mask,
                                 unsigned long long* __restrict__ bits) {
  const int lane = threadIdx.x & 63;
  const int gw = (blockIdx.x * blockDim.x + threadIdx.x) >> 6;
  const int nw = (gridDim.x * blockDim.x) >> 6;
  for (int w = gw; w < SQ * SQ / 64; w += nw) {
    int v = mask[(size_t)w * 64 + lane];
    unsigned long long b = __ballot(v != 0);
    if (lane == 0) bits[(size_t)(w & 31) * SQ + (w >> 5)] = b;
  }
}

// ============================ main kernel ============================
// ROUND-10: occupancy split of the verified round-2 champion (112us).
// Round-8/9 K=32-PV experiment abandoned: its lane exchange is structurally
// wrong (ds_bpermute pulls the SOURCE lane's selected register -- dest-side
// c0/c1 selection is impossible in one pull), and the corrected form adds
// VALU+LDS work to save MFMA slots, which round-5 already showed is the
// wrong trade (VALU chain, not MFMA issue, is critical).
// Change vs round-2: wave owns 16 q (was 32), grid 2048 (was 1024).
// Round-2 was grid-limited to 4 blocks/CU (Occ 35%); LDS cap is 5 blocks
// (5 x 32KB = 160KB). 2048 blocks x half-work -> up to 20 waves/CU (62.5%),
// same total VALU/MFMA work, 2x staging FETCH (~134MB, ~12% HBM - cheap).
// Same-bh blocks stay co-XCD (id = bh mod 64, XCD = id%8 = bh%8).
// Ones-MFMA row-sum + no setprio = the exact 112us configuration.
__global__ __launch_bounds__(256, 4) void attn3(
    const uint4* __restrict__ pk, const uint4* __restrict__ pv,
    const uint2* __restrict__ pm, const float* __restrict__ Qg,
    float* __restrict__ Og) {
  // [0,8K) K buf0, [8K,16K) K buf1, [16K,24K) V buf0, [24K,32K) V buf1
  __shared__ __align__(16) uint8_t smem[32768];

  const int id = blockIdx.x;
  const int bh = id & 63;      // id%8 spreads bh across XCDs; q-blocks of same bh co-XCD
  const int qblk = id >> 6;    // 0..31
  const int t = threadIdx.x;
  const int wave = t >> 6, lane = t & 63, col = lane & 15, quad = lane >> 4;

  const float* Qb = Qg + (size_t)bh * SQ * DH;
  float* Ob = Og + (size_t)bh * SQ * DH;
  const uint4* pkb = pk + (size_t)bh * 32 * 512;
  const uint4* pvb = pv + (size_t)bh * 32 * 512;
  const int q0 = qblk * 64 + wave * 16;
  const int q = q0 + col;      // this lane's query row

  // Q fragments, scale 1/8 * log2(e) folded in (scores emerge in log2 domain)
  const float QSCALE = 0.18033688011112042f;
  bf16x8 qf[2];
#pragma unroll
  for (int j = 0; j < 2; ++j) {
    const float4* p = (const float4*)(Qb + (size_t)q * DH + j * 32 + quad * 8);
    float4 a = p[0], b = p[1];
    bf16x8 f;
    f[0] = (short)f2bf_rne(a.x * QSCALE); f[1] = (short)f2bf_rne(a.y * QSCALE);
    f[2] = (short)f2bf_rne(a.z * QSCALE); f[3] = (short)f2bf_rne(a.w * QSCALE);
    f[4] = (short)f2bf_rne(b.x * QSCALE); f[5] = (short)f2bf_rne(b.y * QSCALE);
    f[6] = (short)f2bf_rne(b.z * QSCALE); f[7] = (short)f2bf_rne(b.w * QSCALE);
    qf[j] = f;
  }

  // loop-invariant LDS byte offsets (XOR swizzle folded into lane constants)
  const unsigned ka0 = col * 128 + ((quad ^ (col & 7)) * 16);
  const unsigned ka1 = col * 128 + (((4 + quad) ^ (col & 7)) * 16);
  unsigned va[4];
#pragma unroll
  for (int kt = 0; kt < 4; ++kt)
    va[kt] = 16384u + col * 128 + (((kt * 4 + quad) ^ col) * 8);
  const char* pmt = (const char*)pm + (size_t)(quad * 2048 + q) * 8;
  const unsigned stK = t * 16;
  const unsigned stV = 16384u + t * 16;

  f32x4 acc[4];  // O^T: row(d_local)=quad*4+r, col=q_local
  f32x4 accl;    // ones-MFMA row-sum (all 4 regs identical)
#pragma unroll
  for (int dt = 0; dt < 4; ++dt)
#pragma unroll
    for (int r = 0; r < 4; ++r) acc[dt][r] = 0.0f;
#pragma unroll
  for (int r = 0; r < 4; ++r) accl[r] = 0.0f;
  bf16x4 vones;
  vones[0] = (short)0x3F80; vones[1] = (short)0x3F80;
  vones[2] = (short)0x3F80; vones[3] = (short)0x3F80;
  const f32x4 fz = {0.0f, 0.0f, 0.0f, 0.0f};

  // prologue: stage tile 0 into buf 0 (async, drained by first barrier)
  gload_lds16(pkb + t,       smem + stK,        lane);
  gload_lds16(pkb + t + 256, smem + stK + 4096, lane);
  gload_lds16(pvb + t,       smem + stV,        lane);
  gload_lds16(pvb + t + 256, smem + stV + 4096, lane);
  unsigned buf = 0;

  for (int tile = 0; tile < 32; ++tile) {
    __syncthreads();  // drains in-flight global_load_lds (vmcnt0) + ob readers done
    const int tn = (tile < 31) ? tile + 1 : 31;
    const unsigned ob = buf ^ 8192u;

    // issue next tile's async loads into the other buffer; they have the whole
    // tile body to land before the next barrier drains them
    const uint4* pkt = pkb + (size_t)tn * 512;
    const uint4* pvt = pvb + (size_t)tn * 512;
    gload_lds16(pkt + t,       smem + ob + stK,        lane);
    gload_lds16(pkt + t + 256, smem + ob + stK + 4096, lane);
    gload_lds16(pvt + t,       smem + ob + stV,        lane);
    gload_lds16(pvt + t + 256, smem + ob + stV + 4096, lane);

    // ---- per kt: QK^T MFMA -> exp2 -> fused pack+mask perm -> PV ----
#pragma unroll
    for (int kt = 0; kt < 4; ++kt) {
      const bf16x8 kf0 = *(const bf16x8*)(smem + buf + kt * 2048 + ka0);
      const bf16x8 kf1 = *(const bf16x8*)(smem + buf + kt * 2048 + ka1);
      const uint2 mw = *(const uint2*)(pmt + (size_t)kt * 65536);

      f32x4 st = __builtin_amdgcn_mfma_f32_16x16x32_bf16(kf0, qf[0], fz, 0, 0, 0);
      st = __builtin_amdgcn_mfma_f32_16x16x32_bf16(kf1, qf[1], st, 0, 0, 0);
      float p0 = fast_exp2(st[0]), p1 = fast_exp2(st[1]);
      float p2 = fast_exp2(st[2]), p3 = fast_exp2(st[3]);

      union { uint32_t u[2]; bf16x4 v; } pw;
      pw.u[0] = pack_sel(p0, p1, mw.x);
      pw.u[1] = pack_sel(p2, p3, mw.y);
      accl = MFMA_PV(vones, pw.v, accl);
#pragma unroll
      for (int dt = 0; dt < 4; ++dt) {
        union { uint2 u2; bf16x4 v; } vf;
        vf.u2 = *(const uint2*)(smem + buf + va[kt] + dt * 2048);
        acc[dt] = MFMA_PV(vf.v, pw.v, acc[dt]);
      }
    }

    buf = ob;
    pmt += 262144;  // next tile's selector block
  }

  // ---- epilogue ----
  {
    float inv = 1.0f / accl[0];
    float* orow = Ob + (size_t)q * DH;
#pragma unroll
    for (int dt = 0; dt < 4; ++dt) {
      float4 o;
      o.x = acc[dt][0] * inv;
      o.y = acc[dt][1] * inv;
      o.z = acc[dt][2] * inv;
      o.w = acc[dt][3] * inv;
      *(float4*)(orow + dt * 16 + quad * 4) = o;
    }
  }
}

// ============================ fallback kernel (round-3 structure) ============================
__global__ __launch_bounds__(512, 4) void attn_fb(
    const float* __restrict__ Qg, const float* __restrict__ Kg,
    const float* __restrict__ Vg, const unsigned long long* __restrict__ mbits,
    const int* __restrict__ mraw, float* __restrict__ Og) {
  __shared__ __align__(16) unsigned short Klds[2][64][72];
  __shared__ __align__(16) uint32_t Vtlds[2][64][36];
  const int id = blockIdx.x;
  const int bh = id & 63;
  const int qblk = id >> 6;
  const int t = threadIdx.x;
  const int wave = t >> 6, lane = t & 63, col = lane & 15, quad = lane >> 4;
  const float* Qb = Qg + (size_t)bh * SQ * DH;
  const float* Kb = Kg + (size_t)bh * SQ * DH;
  const float* Vb = Vg + (size_t)bh * SQ * DH;
  float* Ob = Og + (size_t)bh * SQ * DH;
  const int q0 = qblk * 256 + wave * 32;
  const int skk = t >> 3, sd8 = (t & 7) * 8, skp = t >> 4, sd4 = (t & 15) * 4;
  const float QSCALE = 0.18033688011112042f;
  bf16x8 qf[2][2];
#pragma unroll
  for (int s = 0; s < 2; ++s) {
    int q = q0 + s * 16 + col;
#pragma unroll
    for (int j = 0; j < 2; ++j) {
      const float4* p = (const float4*)(Qb + (size_t)q * DH + j * 32 + quad * 8);
      float4 a = p[0], b = p[1];
      bf16x8 f;
      f[0] = (short)f2bf_rne(a.x * QSCALE); f[1] = (short)f2bf_rne(a.y * QSCALE);
      f[2] = (short)f2bf_rne(a.z * QSCALE); f[3] = (short)f2bf_rne(a.w * QSCALE);
      f[4] = (short)f2bf_rne(b.x * QSCALE); f[5] = (short)f2bf_rne(b.y * QSCALE);
      f[6] = (short)f2bf_rne(b.z * QSCALE); f[7] = (short)f2bf_rne(b.w * QSCALE);
      qf[s][j] = f;
    }
  }
  f32x4 acc[2][4]; f32x4 accl[2];
#pragma unroll
  for (int s = 0; s < 2; ++s) {
#pragma unroll
    for (int dt = 0; dt < 4; ++dt)
#pragma unroll
      for (int r = 0; r < 4; ++r) acc[s][dt][r] = 0.0f;
#pragma unroll
    for (int r = 0; r < 4; ++r) accl[s][r] = 0.0f;
  }
  bf16x4 vones;
  vones[0] = (short)0x3F80; vones[1] = (short)0x3F80;
  vones[2] = (short)0x3F80; vones[3] = (short)0x3F80;
  const f32x4 fz = {0.0f, 0.0f, 0.0f, 0.0f};
  auto load_mask = [&](int ti, unsigned long long m[2]) {
    if (mbits) {
#pragma unroll
      for (int s = 0; s < 2; ++s)
        m[s] = mbits[(size_t)ti * SQ + (q0 + s * 16 + col)];
    } else {
#pragma unroll
      for (int s = 0; s < 2; ++s) {
        int q = q0 + s * 16 + col;
        unsigned long long mm = 0;
#pragma unroll
        for (int j = 0; j < 4; ++j) {
          int4 mi = *(const int4*)(mraw + (size_t)q * SQ + ti * 64 + j * 16 + quad * 4);
          unsigned long long nib = (unsigned long long)((mi.x != 0) | ((mi.y != 0) << 1) |
                                                        ((mi.z != 0) << 2) | ((mi.w != 0) << 3));
          mm |= nib << (j * 16 + quad * 4);
        }
        m[s] = mm;
      }
    }
  };
  {
    const float4* kp = (const float4*)(Kb + (size_t)skk * DH + sd8);
    float4 k0 = kp[0], k1 = kp[1];
    const float* va = Vb + (size_t)(skp * 2) * DH + sd4;
    float4 v0 = *(const float4*)va, v1 = *(const float4*)(va + DH);
    uint4 kw;
    kw.x = pack_hi(k0.x, k0.y); kw.y = pack_hi(k0.z, k0.w);
    kw.z = pack_hi(k1.x, k1.y); kw.w = pack_hi(k1.z, k1.w);
    *(uint4*)&Klds[0][skk][sd8] = kw;
    Vtlds[0][sd4 + 0][skp] = pack_hi(v0.x, v1.x);
    Vtlds[0][sd4 + 1][skp] = pack_hi(v0.y, v1.y);
    Vtlds[0][sd4 + 2][skp] = pack_hi(v0.z, v1.z);
    Vtlds[0][sd4 + 3][skp] = pack_hi(v0.w, v1.w);
  }
  unsigned long long mcur[2];
  load_mask(0, mcur);
  for (int tile = 0; tile < 32; ++tile) {
    __syncthreads();
    const int cb = tile & 1, nb = cb ^ 1;
    const int tn = (tile + 1 < 32) ? tile + 1 : tile;
    const int kkn = tn * 64;
    const float4* kp = (const float4*)(Kb + (size_t)(kkn + skk) * DH + sd8);
    float4 k0 = kp[0], k1 = kp[1];
    const float* va = Vb + (size_t)(kkn + skp * 2) * DH + sd4;
    float4 v0 = *(const float4*)va;
    float4 v1 = *(const float4*)(va + DH);
    unsigned long long mnxt[2];
    load_mask(tn, mnxt);
    uint32_t pfw[2][4][2];
#pragma unroll
    for (int kt = 0; kt < 4; ++kt) {
      const bf16x8 kf0 = *(const bf16x8*)&Klds[cb][kt * 16 + col][quad * 8];
      const bf16x8 kf1 = *(const bf16x8*)&Klds[cb][kt * 16 + col][32 + quad * 8];
#pragma unroll
      for (int s = 0; s < 2; ++s) {
        f32x4 st = __builtin_amdgcn_mfma_f32_16x16x32_bf16(kf0, qf[s][0], fz, 0, 0, 0);
        st = __builtin_amdgcn_mfma_f32_16x16x32_bf16(kf1, qf[s][1], st, 0, 0, 0);
        uint32_t nib = (uint32_t)(mcur[s] >> (kt * 16 + quad * 4)) & 0xFu;
        float p[4];
#pragma unroll
        for (int r = 0; r < 4; ++r)
          p[r] = fast_exp2(((nib >> r) & 1u) ? -1.0e9f : st[r]);
        pfw[s][kt][0] = pack_hi(p[0], p[1]);
        pfw[s][kt][1] = pack_hi(p[2], p[3]);
      }
    }
    {
      uint4 kw;
      kw.x = pack_hi(k0.x, k0.y); kw.y = pack_hi(k0.z, k0.w);
      kw.z = pack_hi(k1.x, k1.y); kw.w = pack_hi(k1.z, k1.w);
      *(uint4*)&Klds[nb][skk][sd8] = kw;
      Vtlds[nb][sd4 + 0][skp] = pack_hi(v0.x, v1.x);
      Vtlds[nb][sd4 + 1][skp] = pack_hi(v0.y, v1.y);
      Vtlds[nb][sd4 + 2][skp] = pack_hi(v0.z, v1.z);
      Vtlds[nb][sd4 + 3][skp] = pack_hi(v0.w, v1.w);
    }
    mcur[0] = mnxt[0]; mcur[1] = mnxt[1];
#pragma unroll
    for (int kt = 0; kt < 4; ++kt) {
      union { uint32_t u[2]; bf16x4 v; } p0, p1;
      p0.u[0] = pfw[0][kt][0]; p0.u[1] = pfw[0][kt][1];
      p1.u[0] = pfw[1][kt][0]; p1.u[1] = pfw[1][kt][1];
      accl[0] = MFMA_PV(vones, p0.v, accl[0]);
      accl[1] = MFMA_PV(vones, p1.v, accl[1]);
#pragma unroll
      for (int dt = 0; dt < 4; ++dt) {
        union { uint2 u2; bf16x4 v; } cv;
        cv.u2 = *(const uint2*)&Vtlds[cb][dt * 16 + col][kt * 8 + quad * 2];
        acc[0][dt] = MFMA_PV(cv.v, p0.v, acc[0][dt]);
        acc[1][dt] = MFMA_PV(cv.v, p1.v, acc[1][dt]);
      }
    }
  }
#pragma unroll
  for (int s = 0; s < 2; ++s) {
    float inv = 1.0f / accl[s][0];
    int q = q0 + s * 16 + col;
    float* orow = Ob + (size_t)q * DH;
#pragma unroll
    for (int dt = 0; dt < 4; ++dt) {
      float4 o;
      o.x = acc[s][dt][0] * inv;
      o.y = acc[s][dt][1] * inv;
      o.z = acc[s][dt][2] * inv;
      o.w = acc[s][dt][3] * inv;
      *(float4*)(orow + dt * 16 + quad * 4) = o;
    }
  }
}

extern "C" void kernel_launch(void* const* d_in, const int* in_sizes, int n_in,
                              void* d_out, int out_size, void* d_ws, size_t ws_size,
                              hipStream_t stream) {
  const float* Q = (const float*)d_in[0];
  const float* K = (const float*)d_in[1];
  const float* V = (const float*)d_in[2];
  const int* mask = (const int*)d_in[3];
  float* out = (float*)d_out;

  const size_t PK_BYTES = (size_t)64 * 32 * 8192;  // 16 MB
  const size_t PV_BYTES = (size_t)64 * 32 * 8192;  // 16 MB
  const size_t PM_BYTES = (size_t)512 * 2048 * 8;  // 8 MB
  const size_t NEED = PK_BYTES + PV_BYTES + PM_BYTES;  // 40 MB

  if (ws_size >= NEED) {
    uint4* pk = (uint4*)d_ws;
    uint2* pv = (uint2*)((char*)d_ws + PK_BYTES);
    uint2* pm = (uint2*)((char*)d_ws + PK_BYTES + PV_BYTES);
    pack_all<<<6144, 256, 0, stream>>>(K, V, mask, pk, pv, pm);
    attn3<<<2048, 256, 0, stream>>>(pk, (uint4*)pv, pm, Q, out);
  } else if (ws_size >= (size_t)SQ * SQ / 8) {
    unsigned long long* bits = (unsigned long long*)d_ws;
    pack_mask_kernel<<<1024, 256, 0, stream>>>(mask, bits);
    attn_fb<<<512, 512, 0, stream>>>(Q, K, V, bits, mask, out);
  } else {
    attn_fb<<<512, 512, 0, stream>>>(Q, K, V, nullptr, mask, out);
  }
}

// Round 11
// 239.876 us; speedup vs baseline: 1.0562x; 1.0344x over previous
//
#include <hip/hip_runtime.h>
#include <stdint.h>

#define SQ 2048
#define DH 64

typedef __attribute__((ext_vector_type(8))) short bf16x8;
typedef __attribute__((ext_vector_type(4))) short bf16x4;
typedef __attribute__((ext_vector_type(4))) float f32x4;

// RNE f32->bf16 (Q only; one-time cost)
static __device__ __forceinline__ unsigned short f2bf_rne(float x) {
  union { float f; uint32_t u; } v; v.f = x;
  uint32_t u = v.u;
  return (unsigned short)((u + 0x7FFFu + ((u >> 16) & 1u)) >> 16);
}

// low16 = bf16_trunc(a), high16 = bf16_trunc(b) -- single v_perm_b32
static __device__ __forceinline__ uint32_t pack_hi(float a, float b) {
  uint32_t au = __float_as_uint(a), bu = __float_as_uint(b);
#if __has_builtin(__builtin_amdgcn_perm)
  return __builtin_amdgcn_perm(bu, au, 0x07060302u);
#else
  return (bu & 0xFFFF0000u) | (au >> 16);
#endif
}

// pack+mask fused: sel bytes 0x02,0x03 pick a's high half; 0x06,0x07 pick b's;
// 0x0C -> constant 0x00 (masked). NOTE: v_perm sel 8..11 are SIGN-REPLICATE,
// not zero -- 12 is the architectural zero byte.
static __device__ __forceinline__ uint32_t pack_sel(float a, float b, uint32_t sel) {
#if __has_builtin(__builtin_amdgcn_perm)
  return __builtin_amdgcn_perm(__float_as_uint(b), __float_as_uint(a), sel);
#else
  uint32_t r = 0;
  uint64_t src = ((uint64_t)__float_as_uint(b) << 32) | __float_as_uint(a);
  for (int i = 0; i < 4; ++i) {
    uint32_t sb = (sel >> (8 * i)) & 0xFF;
    uint32_t byte = (sb < 8) ? (uint32_t)((src >> (8 * sb)) & 0xFF) : 0u;
    r |= byte << (8 * i);
  }
  return r;
#endif
}

static __device__ __forceinline__ float fast_exp2(float x) {
#if __has_builtin(__builtin_amdgcn_exp2f)
  return __builtin_amdgcn_exp2f(x);
#else
  return exp2f(x);
#endif
}

#if __has_builtin(__builtin_amdgcn_mfma_f32_16x16x16_bf16)
#define MFMA_PV(a, b, c) __builtin_amdgcn_mfma_f32_16x16x16_bf16((a), (b), (c), 0, 0, 0)
#else
#define MFMA_PV(a, b, c) __builtin_amdgcn_mfma_f32_16x16x16bf16_1k((a), (b), (c), 0, 0, 0)
#endif

// async global->LDS, 16B per lane. LDS dest is wave-uniform base + lane*16
// (HW rule); global src is per-lane. Frees 16 staging VGPRs vs reg-staging.
typedef __attribute__((address_space(1))) const void as1_const_void;
typedef __attribute__((address_space(3))) void as3_void;
static __device__ __forceinline__ void gload_lds16(const void* g, void* l, int lane) {
#if __has_builtin(__builtin_amdgcn_global_load_lds)
  __builtin_amdgcn_global_load_lds((as1_const_void*)g, (as3_void*)l, 16, 0, 0);
#else
  *(uint4*)((char*)l + lane * 16) = *(const uint4*)g;
#endif
}

// ============================ merged pack kernel ============================
// blocks [0,2048): K/V bf16 pre-pack in LDS-image XOR-swizzled layout.
//   K: per (bh,tile): 64 kk x 8 chunks of 8 bf16; physical chunk cp holds
//      logical c = cp ^ (kk&7).
//   V: per (bh,tile): V^T as [d][u'] uint2 (u = kk/4), u' = u ^ (d&15).
// blocks [2048,6144): mask -> v_perm selector words.
//   pm[g*2048+q] (g = tile*16+kt*4+quad) = uint2; word0 = selector for (kk0,kk1),
//   word1 = (kk2,kk3): keep -> pick bf16 bytes, masked -> 0x0C (zero byte).
__global__ __launch_bounds__(256) void pack_all(const float* __restrict__ K,
                                                const float* __restrict__ V,
                                                const int* __restrict__ mask,
                                                uint4* __restrict__ pk,
                                                uint2* __restrict__ pv,
                                                uint2* __restrict__ pm) {
  const int t = threadIdx.x;
  if (blockIdx.x < 2048) {
    __shared__ uint32_t Vw[64][33];
    const int bt = blockIdx.x;  // bh*32 + tile
    {
      const float* src = K + (size_t)bt * 64 * DH;
      uint4* dst = pk + (size_t)bt * 512;
#pragma unroll
      for (int j = 0; j < 2; ++j) {
        int i = t + j * 256;
        int kk = i >> 3, cp = i & 7;
        int c = cp ^ (kk & 7);
        const float4* s4 = (const float4*)(src + (size_t)kk * DH + c * 8);
        float4 a = s4[0], b = s4[1];
        uint4 w;
        w.x = pack_hi(a.x, a.y); w.y = pack_hi(a.z, a.w);
        w.z = pack_hi(b.x, b.y); w.w = pack_hi(b.z, b.w);
        dst[i] = w;
      }
    }
    {
      const float* src = V + (size_t)bt * 64 * DH;
#pragma unroll
      for (int half = 0; half < 2; ++half) {
        int kp = (t >> 4) + half * 16;
        int d4 = (t & 15) * 4;
        float4 a = *(const float4*)(src + (size_t)(2 * kp) * DH + d4);
        float4 b = *(const float4*)(src + (size_t)(2 * kp + 1) * DH + d4);
        Vw[d4 + 0][kp] = pack_hi(a.x, b.x);
        Vw[d4 + 1][kp] = pack_hi(a.y, b.y);
        Vw[d4 + 2][kp] = pack_hi(a.z, b.z);
        Vw[d4 + 3][kp] = pack_hi(a.w, b.w);
      }
      __syncthreads();
      uint2* dst = pv + (size_t)bt * 1024;
#pragma unroll
      for (int j = 0; j < 4; ++j) {
        int o = t + j * 256;
        int d = o >> 4, up = o & 15;
        int u = up ^ (d & 15);
        uint2 w;
        w.x = Vw[d][2 * u]; w.y = Vw[d][2 * u + 1];
        dst[o] = w;
      }
    }
  } else {
    __shared__ uint2 Lm[16][17];
    const int bid = blockIdx.x - 2048;
    const int qb = bid >> 5, gb = bid & 31;
    {
      int qq = t >> 4, gg = t & 15;
      int4 m = *(const int4*)(mask + (size_t)(qb * 16 + qq) * SQ + (gb * 64 + gg * 4));
      uint2 w;
      w.x = (m.x ? 0x00000C0Cu : 0x00000302u) | (m.y ? 0x0C0C0000u : 0x07060000u);
      w.y = (m.z ? 0x00000C0Cu : 0x00000302u) | (m.w ? 0x0C0C0000u : 0x07060000u);
      Lm[gg][qq] = w;
    }
    __syncthreads();
    {
      int gg = t >> 4, qq = t & 15;
      pm[(size_t)(gb * 16 + gg) * 2048 + qb * 16 + qq] = Lm[gg][qq];
    }
  }
}

// Bitmask for fallback path
__global__ void pack_mask_kernel(const int* __restrict__ mask,
                                 unsigned long long* __restrict__ bits) {
  const int lane = threadIdx.x & 63;
  const int gw = (blockIdx.x * blockDim.x + threadIdx.x) >> 6;
  const int nw = (gridDim.x * blockDim.x) >> 6;
  for (int w = gw; w < SQ * SQ / 64; w += nw) {
    int v = mask[(size_t)w * 64 + lane];
    unsigned long long b = __ballot(v != 0);
    if (lane == 0) bits[(size_t)(w & 31) * SQ + (w >> 5)] = b;
  }
}

// ============================ main kernel ============================
// FINAL (round-11): exact revert to the round-2 champion (attn3 112.3us,
// total 240.0us). Session ledger of structural attempts, all regressed:
//   VALU row-sum + setprio (116.3), barrier-free wave-private (131.5),
//   fused staging (186.6), PV at K=32 (incorrect: ds_bpermute pulls the
//   SOURCE lane's selected register), 16q/wave occupancy split (122.4 --
//   residency is pinned ~3 blocks/CU regardless of grid).
// The structure is stall-bound (no pipe >45%) and sits in a verified local
// optimum; every perturbation added more overhead than it removed.
// Wave owns 32 q (2 sets of 16): K/V fragment LDS reads are q-independent.
// Grid 1024, 4 waves/block, gload_lds double-buffer, ones-MFMA row-sum.
__global__ __launch_bounds__(256, 4) void attn3(
    const uint4* __restrict__ pk, const uint4* __restrict__ pv,
    const uint2* __restrict__ pm, const float* __restrict__ Qg,
    float* __restrict__ Og) {
  // [0,8K) K buf0, [8K,16K) K buf1, [16K,24K) V buf0, [24K,32K) V buf1
  __shared__ __align__(16) uint8_t smem[32768];

  const int id = blockIdx.x;
  const int bh = id & 63;      // id%8 spreads bh across XCDs; q-blocks of same bh co-XCD
  const int qblk = id >> 6;    // 0..15
  const int t = threadIdx.x;
  const int wave = t >> 6, lane = t & 63, col = lane & 15, quad = lane >> 4;

  const float* Qb = Qg + (size_t)bh * SQ * DH;
  float* Ob = Og + (size_t)bh * SQ * DH;
  const uint4* pkb = pk + (size_t)bh * 32 * 512;
  const uint4* pvb = pv + (size_t)bh * 32 * 512;
  const int q0 = qblk * 128 + wave * 32;

  // Q fragments, scale 1/8 * log2(e) folded in (scores emerge in log2 domain)
  const float QSCALE = 0.18033688011112042f;
  bf16x8 qf[2][2];
#pragma unroll
  for (int s = 0; s < 2; ++s) {
    int q = q0 + s * 16 + col;
#pragma unroll
    for (int j = 0; j < 2; ++j) {
      const float4* p = (const float4*)(Qb + (size_t)q * DH + j * 32 + quad * 8);
      float4 a = p[0], b = p[1];
      bf16x8 f;
      f[0] = (short)f2bf_rne(a.x * QSCALE); f[1] = (short)f2bf_rne(a.y * QSCALE);
      f[2] = (short)f2bf_rne(a.z * QSCALE); f[3] = (short)f2bf_rne(a.w * QSCALE);
      f[4] = (short)f2bf_rne(b.x * QSCALE); f[5] = (short)f2bf_rne(b.y * QSCALE);
      f[6] = (short)f2bf_rne(b.z * QSCALE); f[7] = (short)f2bf_rne(b.w * QSCALE);
      qf[s][j] = f;
    }
  }

  // loop-invariant LDS byte offsets (XOR swizzle folded into lane constants)
  const unsigned ka0 = col * 128 + ((quad ^ (col & 7)) * 16);
  const unsigned ka1 = col * 128 + (((4 + quad) ^ (col & 7)) * 16);
  unsigned va[4];
#pragma unroll
  for (int kt = 0; kt < 4; ++kt)
    va[kt] = 16384u + col * 128 + (((kt * 4 + quad) ^ col) * 8);
  const char* pmt = (const char*)pm + (size_t)(quad * 2048 + q0 + col) * 8;

  f32x4 acc[2][4];  // O^T: row(d_local)=quad*4+r, col=q_local
  f32x4 accl[2];    // ones-MFMA row-sum (all 4 regs identical)
#pragma unroll
  for (int s = 0; s < 2; ++s) {
#pragma unroll
    for (int dt = 0; dt < 4; ++dt)
#pragma unroll
      for (int r = 0; r < 4; ++r) acc[s][dt][r] = 0.0f;
#pragma unroll
    for (int r = 0; r < 4; ++r) accl[s][r] = 0.0f;
  }
  bf16x4 vones;
  vones[0] = (short)0x3F80; vones[1] = (short)0x3F80;
  vones[2] = (short)0x3F80; vones[3] = (short)0x3F80;
  const f32x4 fz = {0.0f, 0.0f, 0.0f, 0.0f};

  // prologue: stage tile 0 into buf 0 (async, drained by first barrier)
  gload_lds16(pkb + t,       smem + wave * 1024,         lane);
  gload_lds16(pkb + t + 256, smem + 4096 + wave * 1024,  lane);
  gload_lds16(pvb + t,       smem + 16384 + wave * 1024, lane);
  gload_lds16(pvb + t + 256, smem + 20480 + wave * 1024, lane);
  unsigned buf = 0;

  for (int tile = 0; tile < 32; ++tile) {
    __syncthreads();  // drains in-flight global_load_lds (vmcnt0) + ob readers done
    const int tn = (tile < 31) ? tile + 1 : 31;
    const unsigned ob = buf ^ 8192u;

    // issue next tile's async loads into the other buffer; they have the whole
    // tile body (~4-8K cyc) to land before the next barrier drains them
    const uint4* pkt = pkb + (size_t)tn * 512;
    const uint4* pvt = pvb + (size_t)tn * 512;
    gload_lds16(pkt + t,       smem + ob + wave * 1024,         lane);
    gload_lds16(pkt + t + 256, smem + ob + 4096 + wave * 1024,  lane);
    gload_lds16(pvt + t,       smem + ob + 16384 + wave * 1024, lane);
    gload_lds16(pvt + t + 256, smem + ob + 20480 + wave * 1024, lane);

    // ---- per kt: QK^T MFMA -> exp2 -> fused pack+mask perm -> PV ----
#pragma unroll
    for (int kt = 0; kt < 4; ++kt) {
      const bf16x8 kf0 = *(const bf16x8*)(smem + buf + kt * 2048 + ka0);
      const bf16x8 kf1 = *(const bf16x8*)(smem + buf + kt * 2048 + ka1);
      uint2 mw[2];
#pragma unroll
      for (int s = 0; s < 2; ++s)
        mw[s] = *(const uint2*)(pmt + (size_t)kt * 65536 + s * 128);

      uint32_t pf[2][2];
#pragma unroll
      for (int s = 0; s < 2; ++s) {
        f32x4 st = __builtin_amdgcn_mfma_f32_16x16x32_bf16(kf0, qf[s][0], fz, 0, 0, 0);
        st = __builtin_amdgcn_mfma_f32_16x16x32_bf16(kf1, qf[s][1], st, 0, 0, 0);
        float p0 = fast_exp2(st[0]), p1 = fast_exp2(st[1]);
        float p2 = fast_exp2(st[2]), p3 = fast_exp2(st[3]);
        pf[s][0] = pack_sel(p0, p1, mw[s].x);
        pf[s][1] = pack_sel(p2, p3, mw[s].y);
      }

      union { uint32_t u[2]; bf16x4 v; } pw0, pw1;
      pw0.u[0] = pf[0][0]; pw0.u[1] = pf[0][1];
      pw1.u[0] = pf[1][0]; pw1.u[1] = pf[1][1];
      accl[0] = MFMA_PV(vones, pw0.v, accl[0]);
      accl[1] = MFMA_PV(vones, pw1.v, accl[1]);
      // single-live V fragment: keeps peak VGPR under the 128 budget
#pragma unroll
      for (int dt = 0; dt < 4; ++dt) {
        union { uint2 u2; bf16x4 v; } vf;
        vf.u2 = *(const uint2*)(smem + buf + va[kt] + dt * 2048);
        acc[0][dt] = MFMA_PV(vf.v, pw0.v, acc[0][dt]);
        acc[1][dt] = MFMA_PV(vf.v, pw1.v, acc[1][dt]);
      }
    }

    buf = ob;
    pmt += 262144;  // next tile's selector block
  }

  // ---- epilogue ----
#pragma unroll
  for (int s = 0; s < 2; ++s) {
    float inv = 1.0f / accl[s][0];
    int q = q0 + s * 16 + col;
    float* orow = Ob + (size_t)q * DH;
#pragma unroll
    for (int dt = 0; dt < 4; ++dt) {
      float4 o;
      o.x = acc[s][dt][0] * inv;
      o.y = acc[s][dt][1] * inv;
      o.z = acc[s][dt][2] * inv;
      o.w = acc[s][dt][3] * inv;
      *(float4*)(orow + dt * 16 + quad * 4) = o;
    }
  }
}

// ============================ fallback kernel (round-3 structure) ============================
__global__ __launch_bounds__(512, 4) void attn_fb(
    const float* __restrict__ Qg, const float* __restrict__ Kg,
    const float* __restrict__ Vg, const unsigned long long* __restrict__ mbits,
    const int* __restrict__ mraw, float* __restrict__ Og) {
  __shared__ __align__(16) unsigned short Klds[2][64][72];
  __shared__ __align__(16) uint32_t Vtlds[2][64][36];
  const int id = blockIdx.x;
  const int bh = id & 63;
  const int qblk = id >> 6;
  const int t = threadIdx.x;
  const int wave = t >> 6, lane = t & 63, col = lane & 15, quad = lane >> 4;
  const float* Qb = Qg + (size_t)bh * SQ * DH;
  const float* Kb = Kg + (size_t)bh * SQ * DH;
  const float* Vb = Vg + (size_t)bh * SQ * DH;
  float* Ob = Og + (size_t)bh * SQ * DH;
  const int q0 = qblk * 256 + wave * 32;
  const int skk = t >> 3, sd8 = (t & 7) * 8, skp = t >> 4, sd4 = (t & 15) * 4;
  const float QSCALE = 0.18033688011112042f;
  bf16x8 qf[2][2];
#pragma unroll
  for (int s = 0; s < 2; ++s) {
    int q = q0 + s * 16 + col;
#pragma unroll
    for (int j = 0; j < 2; ++j) {
      const float4* p = (const float4*)(Qb + (size_t)q * DH + j * 32 + quad * 8);
      float4 a = p[0], b = p[1];
      bf16x8 f;
      f[0] = (short)f2bf_rne(a.x * QSCALE); f[1] = (short)f2bf_rne(a.y * QSCALE);
      f[2] = (short)f2bf_rne(a.z * QSCALE); f[3] = (short)f2bf_rne(a.w * QSCALE);
      f[4] = (short)f2bf_rne(b.x * QSCALE); f[5] = (short)f2bf_rne(b.y * QSCALE);
      f[6] = (short)f2bf_rne(b.z * QSCALE); f[7] = (short)f2bf_rne(b.w * QSCALE);
      qf[s][j] = f;
    }
  }
  f32x4 acc[2][4]; f32x4 accl[2];
#pragma unroll
  for (int s = 0; s < 2; ++s) {
#pragma unroll
    for (int dt = 0; dt < 4; ++dt)
#pragma unroll
      for (int r = 0; r < 4; ++r) acc[s][dt][r] = 0.0f;
#pragma unroll
    for (int r = 0; r < 4; ++r) accl[s][r] = 0.0f;
  }
  bf16x4 vones;
  vones[0] = (short)0x3F80; vones[1] = (short)0x3F80;
  vones[2] = (short)0x3F80; vones[3] = (short)0x3F80;
  const f32x4 fz = {0.0f, 0.0f, 0.0f, 0.0f};
  auto load_mask = [&](int ti, unsigned long long m[2]) {
    if (mbits) {
#pragma unroll
      for (int s = 0; s < 2; ++s)
        m[s] = mbits[(size_t)ti * SQ + (q0 + s * 16 + col)];
    } else {
#pragma unroll
      for (int s = 0; s < 2; ++s) {
        int q = q0 + s * 16 + col;
        unsigned long long mm = 0;
#pragma unroll
        for (int j = 0; j < 4; ++j) {
          int4 mi = *(const int4*)(mraw + (size_t)q * SQ + ti * 64 + j * 16 + quad * 4);
          unsigned long long nib = (unsigned long long)((mi.x != 0) | ((mi.y != 0) << 1) |
                                                        ((mi.z != 0) << 2) | ((mi.w != 0) << 3));
          mm |= nib << (j * 16 + quad * 4);
        }
        m[s] = mm;
      }
    }
  };
  {
    const float4* kp = (const float4*)(Kb + (size_t)skk * DH + sd8);
    float4 k0 = kp[0], k1 = kp[1];
    const float* va = Vb + (size_t)(skp * 2) * DH + sd4;
    float4 v0 = *(const float4*)va, v1 = *(const float4*)(va + DH);
    uint4 kw;
    kw.x = pack_hi(k0.x, k0.y); kw.y = pack_hi(k0.z, k0.w);
    kw.z = pack_hi(k1.x, k1.y); kw.w = pack_hi(k1.z, k1.w);
    *(uint4*)&Klds[0][skk][sd8] = kw;
    Vtlds[0][sd4 + 0][skp] = pack_hi(v0.x, v1.x);
    Vtlds[0][sd4 + 1][skp] = pack_hi(v0.y, v1.y);
    Vtlds[0][sd4 + 2][skp] = pack_hi(v0.z, v1.z);
    Vtlds[0][sd4 + 3][skp] = pack_hi(v0.w, v1.w);
  }
  unsigned long long mcur[2];
  load_mask(0, mcur);
  for (int tile = 0; tile < 32; ++tile) {
    __syncthreads();
    const int cb = tile & 1, nb = cb ^ 1;
    const int tn = (tile + 1 < 32) ? tile + 1 : tile;
    const int kkn = tn * 64;
    const float4* kp = (const float4*)(Kb + (size_t)(kkn + skk) * DH + sd8);
    float4 k0 = kp[0], k1 = kp[1];
    const float* va = Vb + (size_t)(kkn + skp * 2) * DH + sd4;
    float4 v0 = *(const float4*)va;
    float4 v1 = *(const float4*)(va + DH);
    unsigned long long mnxt[2];
    load_mask(tn, mnxt);
    uint32_t pfw[2][4][2];
#pragma unroll
    for (int kt = 0; kt < 4; ++kt) {
      const bf16x8 kf0 = *(const bf16x8*)&Klds[cb][kt * 16 + col][quad * 8];
      const bf16x8 kf1 = *(const bf16x8*)&Klds[cb][kt * 16 + col][32 + quad * 8];
#pragma unroll
      for (int s = 0; s < 2; ++s) {
        f32x4 st = __builtin_amdgcn_mfma_f32_16x16x32_bf16(kf0, qf[s][0], fz, 0, 0, 0);
        st = __builtin_amdgcn_mfma_f32_16x16x32_bf16(kf1, qf[s][1], st, 0, 0, 0);
        uint32_t nib = (uint32_t)(mcur[s] >> (kt * 16 + quad * 4)) & 0xFu;
        float p[4];
#pragma unroll
        for (int r = 0; r < 4; ++r)
          p[r] = fast_exp2(((nib >> r) & 1u) ? -1.0e9f : st[r]);
        pfw[s][kt][0] = pack_hi(p[0], p[1]);
        pfw[s][kt][1] = pack_hi(p[2], p[3]);
      }
    }
    {
      uint4 kw;
      kw.x = pack_hi(k0.x, k0.y); kw.y = pack_hi(k0.z, k0.w);
      kw.z = pack_hi(k1.x, k1.y); kw.w = pack_hi(k1.z, k1.w);
      *(uint4*)&Klds[nb][skk][sd8] = kw;
      Vtlds[nb][sd4 + 0][skp] = pack_hi(v0.x, v1.x);
      Vtlds[nb][sd4 + 1][skp] = pack_hi(v0.y, v1.y);
      Vtlds[nb][sd4 + 2][skp] = pack_hi(v0.z, v1.z);
      Vtlds[nb][sd4 + 3][skp] = pack_hi(v0.w, v1.w);
    }
    mcur[0] = mnxt[0]; mcur[1] = mnxt[1];
#pragma unroll
    for (int kt = 0; kt < 4; ++kt) {
      union { uint32_t u[2]; bf16x4 v; } p0, p1;
      p0.u[0] = pfw[0][kt][0]; p0.u[1] = pfw[0][kt][1];
      p1.u[0] = pfw[1][kt][0]; p1.u[1] = pfw[1][kt][1];
      accl[0] = MFMA_PV(vones, p0.v, accl[0]);
      accl[1] = MFMA_PV(vones, p1.v, accl[1]);
#pragma unroll
      for (int dt = 0; dt < 4; ++dt) {
        union { uint2 u2; bf16x4 v; } cv;
        cv.u2 = *(const uint2*)&Vtlds[cb][dt * 16 + col][kt * 8 + quad * 2];
        acc[0][dt] = MFMA_PV(cv.v, p0.v, acc[0][dt]);
        acc[1][dt] = MFMA_PV(cv.v, p1.v, acc[1][dt]);
      }
    }
  }
#pragma unroll
  for (int s = 0; s < 2; ++s) {
    float inv = 1.0f / accl[s][0];
    int q = q0 + s * 16 + col;
    float* orow = Ob + (size_t)q * DH;
#pragma unroll
    for (int dt = 0; dt < 4; ++dt) {
      float4 o;
      o.x = acc[s][dt][0] * inv;
      o.y = acc[s][dt][1] * inv;
      o.z = acc[s][dt][2] * inv;
      o.w = acc[s][dt][3] * inv;
      *(float4*)(orow + dt * 16 + quad * 4) = o;
    }
  }
}

extern "C" void kernel_launch(void* const* d_in, const int* in_sizes, int n_in,
                              void* d_out, int out_size, void* d_ws, size_t ws_size,
                              hipStream_t stream) {
  const float* Q = (const float*)d_in[0];
  const float* K = (const float*)d_in[1];
  const float* V = (const float*)d_in[2];
  const int* mask = (const int*)d_in[3];
  float* out = (float*)d_out;

  const size_t PK_BYTES = (size_t)64 * 32 * 8192;  // 16 MB
  const size_t PV_BYTES = (size_t)64 * 32 * 8192;  // 16 MB
  const size_t PM_BYTES = (size_t)512 * 2048 * 8;  // 8 MB
  const size_t NEED = PK_BYTES + PV_BYTES + PM_BYTES;  // 40 MB

  if (ws_size >= NEED) {
    uint4* pk = (uint4*)d_ws;
    uint2* pv = (uint2*)((char*)d_ws + PK_BYTES);
    uint2* pm = (uint2*)((char*)d_ws + PK_BYTES + PV_BYTES);
    pack_all<<<6144, 256, 0, stream>>>(K, V, mask, pk, pv, pm);
    attn3<<<1024, 256, 0, stream>>>(pk, (uint4*)pv, pm, Q, out);
  } else if (ws_size >= (size_t)SQ * SQ / 8) {
    unsigned long long* bits = (unsigned long long*)d_ws;
    pack_mask_kernel<<<1024, 256, 0, stream>>>(mask, bits);
    attn_fb<<<512, 512, 0, stream>>>(Q, K, V, bits, mask, out);
  } else {
    attn_fb<<<512, 512, 0, stream>>>(Q, K, V, nullptr, mask, out);
  }
}